// Round 15
// baseline (189.189 us; speedup 1.0000x reference)
//
#include <hip/hip_runtime.h>
#include <math.h>

#define TPB 256
static inline int cdiv(int a, int b) { return (a + b - 1) / b; }

typedef short bf8 __attribute__((ext_vector_type(8)));   // 8 bf16 (4 VGPRs)
typedef float f4 __attribute__((ext_vector_type(4)));    // mfma acc

__device__ inline float b2f(unsigned short u) {
    union { unsigned int i; float f; } v; v.i = ((unsigned int)u) << 16; return v.f;
}
__device__ inline short f2b(float f) {
    union { float f; unsigned int u; } v; v.f = f;
    unsigned int r = v.u + 0x7FFF + ((v.u >> 16) & 1);
    return (short)(r >> 16);
}

// direct global->LDS DMA, 16B per lane; l must be the wave-uniform base
__device__ __forceinline__ void gl_lds16(const short* g, short* l) {
    __builtin_amdgcn_global_load_lds(
        reinterpret_cast<const unsigned int*>(g),
        reinterpret_cast<unsigned int*>(l), 16, 0, 0);
}

// ---------------- workspace offsets (in shorts) ----------------
#define OW1   0               // [11][96][64]
#define OW2   67584           // [5][256][512]  (480 pad 512)
#define OW3   722944          // [3][384][768]
#define OW4   1607680         // [3][384][1152]
#define OW5   2934784         // [3][256][1152]
#define OWRC  3819520         // [3][512][768]  wr|wc
#define OWH1  4999168         // 2 x [256][256]
#define OZT   5130240         // 2 x [8][16][256]
#define OWH2  5195776         // [30][256] bf16: ch_w2(10) | rh_w2(20)
#define OBIAS 5203456         // 1024 f32 (2048 shorts): br|bc|chb1|rhb1
#define OACT1 5205504
#define OP1   7062368
#define OACTB 7521472
#define OXF   9520064
#define OCRC  9695168

#define ACT2_OFF  0
#define POOL2_OFF 1083648
#define ACT3_OFF  1347840
#define ACT4_OFF  1695488

// ---------------- fused prep ----------------
__global__ __launch_bounds__(256) void wprep_k(
        const float* __restrict__ bb_w1, const float* __restrict__ bb_w2,
        const float* __restrict__ bb_w3, const float* __restrict__ bb_w4,
        const float* __restrict__ bb_w5,
        const float* __restrict__ wr, const float* __restrict__ wc,
        const float* __restrict__ ch_w1, const float* __restrict__ rh_w1,
        const float* __restrict__ ch_w2, const float* __restrict__ rh_w2,
        const float* __restrict__ z_cls, const float* __restrict__ z_reg,
        const float* __restrict__ br, const float* __restrict__ bc,
        const float* __restrict__ chb1, const float* __restrict__ rhb1,
        const float* __restrict__ x,
        short* __restrict__ W, float* __restrict__ biasf,
        short* __restrict__ xb) {
    __shared__ float lds[3465];   // up to K2*(C+1) = 9*385
    int bid = blockIdx.x;
    int t = threadIdx.x;

    if (bid < 1792) {
        const float* src;
        short* dst;
        int C, K2, Ot, KwC, orow;
        if (bid < 384)       { int o = bid;        C = 256; K2 = 9;  src = bb_w3 + (size_t)o * 2304; dst = W + OW3;  Ot = 384; KwC = 768;  orow = o; }
        else if (bid < 768)  { int o = bid - 384;  C = 384; K2 = 9;  src = bb_w4 + (size_t)o * 3456; dst = W + OW4;  Ot = 384; KwC = 1152; orow = o; }
        else if (bid < 1024) { int o = bid - 768;  C = 384; K2 = 9;  src = bb_w5 + (size_t)o * 3456; dst = W + OW5;  Ot = 256; KwC = 1152; orow = o; }
        else if (bid < 1280) { int o = bid - 1024; C = 256; K2 = 9;  src = wr    + (size_t)o * 2304; dst = W + OWRC; Ot = 512; KwC = 768;  orow = o; }
        else if (bid < 1536) { int o = bid - 1280; C = 256; K2 = 9;  src = wc    + (size_t)o * 2304; dst = W + OWRC; Ot = 512; KwC = 768;  orow = o + 256; }
        else                 { int o = bid - 1536; C = 96;  K2 = 25; src = bb_w2 + (size_t)o * 2400; dst = W + OW2;  Ot = 256; KwC = 512;  orow = o; }

        int n = C * K2;
        int Cp = C + 1;
        if (K2 == 9) {
            for (int i = t; i < n; i += 256) {
                int kk = i % 9, c = i / 9;
                lds[kk * Cp + c] = src[i];
            }
            __syncthreads();
#pragma unroll
            for (int kk = 0; kk < 9; ++kk) {
                int ki = kk / 3, kj = kk % 3;
                short* rowb = dst + ((size_t)ki * Ot + orow) * KwC + kj * C;
                for (int c = t; c < C; c += 256)
                    rowb[c] = f2b(lds[kk * Cp + c]);
            }
        } else {
            for (int i = t; i < n; i += 256) {
                int kk = i % 25, c = i / 25;
                lds[kk * Cp + c] = src[i];
            }
            __syncthreads();
            for (int kk = 0; kk < 25; ++kk) {
                int ki = kk / 5, kj = kk % 5;
                short* rowb = dst + ((size_t)ki * Ot + orow) * KwC + kj * C;
                if (t < C) rowb[t] = f2b(lds[kk * Cp + t]);
            }
            if (t < 160) {
                int ki = t / 32, kp = 480 + (t & 31);
                dst[((size_t)ki * Ot + orow) * KwC + kp] = 0;
            }
        }
        return;
    }

    int fidx = (bid - 1792) * 256 + t;
    if (fidx < 67584) {                               // Wt1 [11][96][64]
        int k = fidx & 63, o = (fidx >> 6) % 96, ki = fidx / (64 * 96);
        float v = 0.f;
        if (k < 33) v = bb_w1[o * 363 + (k % 3) * 121 + ki * 11 + (k / 3)];
        W[fidx] = f2b(v);
    } else if (fidx < 198656) {                       // Wh1 [256][256] x2
        int i = fidx - 67584;
        const float* src = (i < 65536) ? ch_w1 : rh_w1;
        W[OWH1 + i] = f2b(src[i & 65535]);
    } else if (fidx < 206336) {                       // Wh2 [30][256]
        int i = fidx - 198656;
        int o = i >> 8, c = i & 255;
        float v = (o < 10) ? ch_w2[o * 256 + c] : rh_w2[(o - 10) * 256 + c];
        W[OWH2 + i] = f2b(v);
    } else if (fidx < 271872) {                       // zt [8][16][256] x2
        int i = fidx - 206336;
        const float* src = (i < 32768) ? z_cls : z_reg;
        int j = i & 32767;
        int c = j & 255, k = (j >> 8) & 15, m = j >> 12;
        W[OZT + i] = f2b(src[m * 4096 + c * 16 + k]);
    } else if (fidx < 272896) {                       // biases 1024 f32
        int i = fidx - 271872;
        const float* src = (i < 256) ? br : (i < 512) ? bc : (i < 768) ? chb1 : rhb1;
        biasf[i] = src[i & 255];
    } else {                                          // xb f32->bf16
        int i = fidx - 272896;
        if (i < 247107) xb[i] = f2b(x[i]);
    }
}

// ---- implicit-GEMM: global_load_lds staging, 3-buffer rotation, counted vmcnt ----
// Per step: wait vmcnt(IN_FLIGHT) [buf s landed; buf s+1 stays in flight ACROSS the
// barrier] -> raw s_barrier -> issue DMA for buf s+2 -> MFMA on buf s. Load->use
// window = 2 full steps (> HBM latency). Never drains the newest loads (T4).
// Buffer-reuse safety: buf s+2 == buf s-1, whose readers all passed this barrier.
template <int BKC>
__global__ __launch_bounds__(256) void gemm_k(
        const short* __restrict__ in, const short* __restrict__ wt,
        const float* __restrict__ bias, short* __restrict__ out,
        int M, int N, int Wo, int CinW, int Cin,
        int S, int SPR, int aWrap, int bWrap, int KwCp,
        int relu, int msplit, int wsec, int bsec, int nt) {
    constexpr int BK = BKC * 32;       // shorts per K-step row
    constexpr int CPR = BK / 8;        // 16B chunks per row
    constexpr int RPR = 256 / CPR;     // rows staged per q-round
    __shared__ short sa[3][64 * BK];
    __shared__ short sb[3][64 * BK];

    int bid = blockIdx.x;
    int m0 = (bid / nt) * 64, n0 = (bid % nt) * 64;
    int t = threadIdx.x;
    int lane = t & 63;
    int wid = t >> 6, wm = wid >> 1, wn = wid & 1;
    int sec = (m0 >= msplit) ? 1 : 0;
    const short* wts = wt + (size_t)sec * wsec;
    const float* bs = bias + sec * bsec;

    int rql = t / CPR;
    int cpos = t % CPR;
    int gch = (cpos ^ (rql & 7)) * 8;   // swizzled source chunk offset (shorts)

    const short* pA[BKC];
    const short* pB[BKC];
#pragma unroll
    for (int q = 0; q < BKC; ++q) {
        int mr = m0 + q * RPR + rql; if (mr > M - 1) mr = M - 1;
        int oy = mr / Wo, ox = mr - oy * Wo;
        pA[q] = in + (size_t)oy * CinW + (size_t)ox * Cin + gch;
        int nr = n0 + q * RPR + rql; if (nr > N - 1) nr = N - 1;
        pB[q] = wts + (size_t)nr * KwCp + gch;
    }
    int dstw = wid * 512;               // wave-uniform LDS base (shorts) within q-section

    int cg = lane >> 4, lm7 = lane & 7;
    int arowb = (wm * 32 + (lane & 15)) * BK;
    int browb = (wn * 32 + (lane & 15)) * BK;

    f4 acc[2][2] = {};
    int srow = 0;

#define ISSUE(buf)                                                            \
    do {                                                                      \
        _Pragma("unroll")                                                     \
        for (int q = 0; q < BKC; ++q) {                                       \
            gl_lds16(pA[q], &sa[buf][q * (RPR * BK) + dstw]);                 \
            gl_lds16(pB[q], &sb[buf][q * (RPR * BK) + dstw]);                 \
        }                                                                     \
        if (++srow == SPR) {                                                  \
            srow = 0;                                                         \
            _Pragma("unroll")                                                 \
            for (int q = 0; q < BKC; ++q) { pA[q] += aWrap; pB[q] += bWrap; } \
        } else {                                                              \
            _Pragma("unroll")                                                 \
            for (int q = 0; q < BKC; ++q) { pA[q] += BK; pB[q] += BK; }       \
        }                                                                     \
    } while (0)

#define MFMA_STEP(buf)                                                        \
    do {                                                                      \
        const short* A = sa[buf];                                             \
        const short* B = sb[buf];                                             \
        _Pragma("unroll")                                                     \
        for (int kc = 0; kc < BKC; ++kc) {                                    \
            int ch = (((kc << 2) | cg) ^ lm7) * 8;                            \
            bf8 a0 = *(const bf8*)&A[arowb + ch];                             \
            bf8 a1 = *(const bf8*)&A[arowb + 16 * BK + ch];                   \
            bf8 b0 = *(const bf8*)&B[browb + ch];                             \
            bf8 b1 = *(const bf8*)&B[browb + 16 * BK + ch];                   \
            acc[0][0] = __builtin_amdgcn_mfma_f32_16x16x32_bf16(a0, b0, acc[0][0], 0, 0, 0); \
            acc[0][1] = __builtin_amdgcn_mfma_f32_16x16x32_bf16(a0, b1, acc[0][1], 0, 0, 0); \
            acc[1][0] = __builtin_amdgcn_mfma_f32_16x16x32_bf16(a1, b0, acc[1][0], 0, 0, 0); \
            acc[1][1] = __builtin_amdgcn_mfma_f32_16x16x32_bf16(a1, b1, acc[1][1], 0, 0, 0); \
        }                                                                     \
    } while (0)

    // prologue: 2 steps in flight
    ISSUE(0);
    if (S > 1) ISSUE(1);

    int b = 0;
    for (int s = 0; s < S; ++s) {
        if (s + 1 < S) {
            // wait for buf s only; buf s+1's loads stay in flight across the barrier
            if constexpr (BKC == 4) asm volatile("s_waitcnt vmcnt(8)" ::: "memory");
            else                    asm volatile("s_waitcnt vmcnt(4)" ::: "memory");
        } else {
            asm volatile("s_waitcnt vmcnt(0)" ::: "memory");
        }
        asm volatile("s_barrier" ::: "memory");
        __builtin_amdgcn_sched_barrier(0);
        if (s + 2 < S) ISSUE((s + 2) % 3);
        MFMA_STEP(b);
        b = (b == 2) ? 0 : b + 1;
    }
#undef ISSUE
#undef MFMA_STEP

#pragma unroll
    for (int i = 0; i < 2; ++i) {
#pragma unroll
        for (int j = 0; j < 2; ++j) {
            int gm_base = m0 + wm * 32 + i * 16 + (lane >> 4) * 4;
            int gn = n0 + wn * 32 + j * 16 + (lane & 15);
            if (gn < N) {
                float bv = bs[gn];
#pragma unroll
                for (int r = 0; r < 4; ++r) {
                    int gm = gm_base + r;
                    if (gm < M) {
                        float v = acc[i][j][r] + bv;
                        if (relu) v = fmaxf(v, 0.f);
                        out[(size_t)gm * N + gn] = f2b(v);
                    }
                }
            }
        }
    }
}

// ---------------- maxpool 3x3 s2 + relu, NHWC bf16 ----------------
__global__ void pool_k(const short* __restrict__ in, short* __restrict__ out,
                       int C8, int Win, int Ho) {
    int idx = blockIdx.x * blockDim.x + threadIdx.x;
    int total = Ho * Ho * C8;
    if (idx >= total) return;
    int c8 = idx % C8;
    int p = idx / C8;
    int oy = p / Ho, ox = p % Ho;
    int C = C8 * 8;
    float mx[8];
#pragma unroll
    for (int e = 0; e < 8; ++e) mx[e] = -INFINITY;
#pragma unroll
    for (int ki = 0; ki < 3; ++ki)
#pragma unroll
        for (int kj = 0; kj < 3; ++kj) {
            const bf8 v = *(const bf8*)(in + ((size_t)(oy * 2 + ki) * Win + ox * 2 + kj) * C + c8 * 8);
#pragma unroll
            for (int e = 0; e < 8; ++e) mx[e] = fmaxf(mx[e], b2f((unsigned short)v[e]));
        }
    bf8 o;
#pragma unroll
    for (int e = 0; e < 8; ++e) o[e] = f2b(fmaxf(mx[e], 0.f));
    *(bf8*)(out + (size_t)p * C + c8 * 8) = o;
}

// ---------------- depthwise 4x4 correlation, both halves in one dispatch ----------------
__global__ void dwcorr_k(const short* __restrict__ crcb, const short* __restrict__ zt,
                         short* __restrict__ corr) {
    int idx = blockIdx.x * blockDim.x + threadIdx.x;
    if (idx >= 2 * 903168) return;
    int half = idx / 903168;
    int r = idx - half * 903168;
    int c = r & 255;
    int l = (r >> 8) % 441;
    int mb = r / (441 * 256);
    int y = l / 21, xx = l % 21;
    const short* ip = crcb + half * 256 + (size_t)(y * 24 + xx) * 512 + c;
    const short* zp = zt + half * 32768 + mb * 4096 + c;
    float acc = 0.f;
#pragma unroll
    for (int ki = 0; ki < 4; ++ki)
#pragma unroll
        for (int kj = 0; kj < 4; ++kj)
            acc = fmaf(b2f((unsigned short)ip[(ki * 24 + kj) * 512]),
                       b2f((unsigned short)zp[(ki * 4 + kj) * 256]), acc);
    corr[((size_t)(half * 3584 + mb * 441 + l)) * 256 + c] = f2b(acc);
}

// ---------------- fused head layer-2 + decode, 3 parallel output groups ----------------
__global__ void head2epi_k(const short* __restrict__ hid, const short* __restrict__ wh2,
                           const float* __restrict__ chb2, const float* __restrict__ rhb2,
                           const float* __restrict__ a0, const float* __restrict__ a1,
                           const float* __restrict__ a2, const float* __restrict__ a3,
                           float* __restrict__ out) {
    const int Ntot = 8 * 2205;
    int idx = blockIdx.x * blockDim.x + threadIdx.x;
    if (idx >= 3 * Ntot) return;
    int g = idx / Ntot;
    int r = idx - g * Ntot;
    int m = r / 2205, j = r % 2205;
    int a = j / 441, pos = j % 441;
    int ml = m * 441 + pos;
    const short* h = hid + (size_t)((g == 0) ? ml : 3584 + ml) * 256;
    int row0, row1;
    float acc0, acc1;
    if (g == 0)      { row0 = a;      row1 = 5 + a;  acc0 = chb2[a];      acc1 = chb2[5 + a];  }
    else if (g == 1) { row0 = 10 + a; row1 = 15 + a; acc0 = rhb2[a];      acc1 = rhb2[5 + a];  }
    else             { row0 = 20 + a; row1 = 25 + a; acc0 = rhb2[10 + a]; acc1 = rhb2[15 + a]; }
    const short* w0 = wh2 + row0 * 256;
    const short* w1 = wh2 + row1 * 256;
    for (int c = 0; c < 256; c += 8) {
        bf8 hv = *(const bf8*)(h + c);
        bf8 w0v = *(const bf8*)(w0 + c);
        bf8 w1v = *(const bf8*)(w1 + c);
#pragma unroll
        for (int e = 0; e < 8; ++e) {
            float hf = b2f((unsigned short)hv[e]);
            acc0 = fmaf(hf, b2f((unsigned short)w0v[e]), acc0);
            acc1 = fmaf(hf, b2f((unsigned short)w1v[e]), acc1);
        }
    }
    if (g == 0) {
        out[4 * Ntot + r] = 1.f / (1.f + expf(acc0 - acc1));
    } else if (g == 1) {
        out[0 * Ntot + r] = fmaf(acc0, a2[r], a0[r]);
        out[1 * Ntot + r] = fmaf(acc1, a3[r], a1[r]);
    } else {
        out[2 * Ntot + r] = expf(acc0) * a2[r];
        out[3 * Ntot + r] = expf(acc1) * a3[r];
    }
}

extern "C" void kernel_launch(void* const* d_in, const int* in_sizes, int n_in,
                              void* d_out, int out_size, void* d_ws, size_t ws_size,
                              hipStream_t stream) {
    const float* x     = (const float*)d_in[0];
    const float* z_reg = (const float*)d_in[1];
    const float* z_cls = (const float*)d_in[2];
    const float* bb_w1 = (const float*)d_in[3];
    const float* bb_b1 = (const float*)d_in[4];
    const float* bb_w2 = (const float*)d_in[5];
    const float* bb_b2 = (const float*)d_in[6];
    const float* bb_w3 = (const float*)d_in[7];
    const float* bb_b3 = (const float*)d_in[8];
    const float* bb_w4 = (const float*)d_in[9];
    const float* bb_b4 = (const float*)d_in[10];
    const float* bb_w5 = (const float*)d_in[11];
    const float* bb_b5 = (const float*)d_in[12];
    const float* wr    = (const float*)d_in[13];
    const float* br    = (const float*)d_in[14];
    const float* wc    = (const float*)d_in[15];
    const float* bc    = (const float*)d_in[16];
    const float* rh_w1 = (const float*)d_in[17];
    const float* rh_b1 = (const float*)d_in[18];
    const float* rh_w2 = (const float*)d_in[19];
    const float* rh_b2 = (const float*)d_in[20];
    const float* ch_w1 = (const float*)d_in[21];
    const float* ch_b1 = (const float*)d_in[22];
    const float* ch_w2 = (const float*)d_in[23];
    const float* ch_b2 = (const float*)d_in[24];
    const float* anc0  = (const float*)d_in[25];
    const float* anc1  = (const float*)d_in[26];
    const float* anc2  = (const float*)d_in[27];
    const float* anc3  = (const float*)d_in[28];

    short* sws  = (short*)d_ws;
    short* W    = sws;
    float* biasf = (float*)(sws + OBIAS);
    short* act1 = sws + OACT1;              // later: hid
    short* pool1 = sws + OP1;
    short* actB = sws + OACTB;
    short* xb   = actB;
    short* act2 = actB + ACT2_OFF;
    short* pool2 = actB + POOL2_OFF;
    short* act3 = actB + ACT3_OFF;
    short* act4 = actB + ACT4_OFF;
    short* corr = actB;
    short* xf   = sws + OXF;
    short* crcb = sws + OCRC;
    short* hid  = act1;

    const int BIG = 1 << 30;

    // 1. fused prep
    wprep_k<<<1792 + 2032, 256, 0, stream>>>(
        bb_w1, bb_w2, bb_w3, bb_w4, bb_w5, wr, wc, ch_w1, rh_w1, ch_w2, rh_w2,
        z_cls, z_reg, br, bc, ch_b1, rh_b1, x, W, biasf, xb);

    // 2. conv1: M=19321 N=96, 11 ki-rows of K=64 (33 real)
    gemm_k<2><<<302 * 2, 256, 0, stream>>>(
        xb, W + OW1, bb_b1, act1,
        19321, 96, 139, 1722, 6,
        11, 1, 861, 6144, 64, 0, BIG, 0, 0, 2);
    pool_k<<<cdiv(69 * 69 * 12, TPB), TPB, 0, stream>>>(act1, pool1, 12, 139, 69);

    // 3. conv2: M=4225 N=256, K=5x512(480 real), S=20
    gemm_k<4><<<67 * 4, 256, 0, stream>>>(
        pool1, W + OW2, bb_b2, act2,
        4225, 256, 65, 6624, 96,
        20, 4, 6240, 130688, 512, 0, BIG, 0, 0, 4);
    pool_k<<<cdiv(32 * 32 * 32, TPB), TPB, 0, stream>>>(act2, pool2, 32, 65, 32);

    // 4. conv3: S=18
    gemm_k<4><<<15 * 6, 256, 0, stream>>>(
        pool2, W + OW3, bb_b3, act3,
        900, 384, 30, 8192, 256,
        18, 6, 7552, 294272, 768, 1, BIG, 0, 0, 6);

    // 5. conv4: S=27
    gemm_k<4><<<13 * 6, 256, 0, stream>>>(
        act3, W + OW4, bb_b4, act4,
        784, 384, 28, 11520, 384,
        27, 9, 10496, 441344, 1152, 1, BIG, 0, 0, 6);

    // 6. conv5: S=27 (no relu)
    gemm_k<4><<<11 * 4, 256, 0, stream>>>(
        act4, W + OW5, bb_b5, xf,
        676, 256, 26, 10752, 384,
        27, 9, 9728, 293888, 1152, 0, BIG, 0, 0, 4);

    // 7. conv_reg2|conv_cls2 fused: N=512, S=18
    gemm_k<4><<<9 * 8, 256, 0, stream>>>(
        xf, W + OWRC, biasf, crcb,
        576, 512, 24, 6656, 256,
        18, 6, 6016, 392576, 768, 1, BIG, 0, 0, 8);

    // 8. depthwise correlation (both halves)
    dwcorr_k<<<cdiv(2 * 903168, TPB), TPB, 0, stream>>>(crcb, W + OZT, corr);

    // 9. head layer-1: M=7112 (split 3584), K=256, S=2
    gemm_k<4><<<112 * 4, 256, 0, stream>>>(
        corr, W + OWH1, biasf + 512, hid,
        7112, 256, 7112, 0, 256,
        2, 2, 0, 0, 256, 1, 3584, 65536, 256, 4);

    // 10. fused head layer-2 + decode
    head2epi_k<<<cdiv(3 * 8 * 2205, TPB), TPB, 0, stream>>>(
        hid, W + OWH2, ch_b2, rh_b2, anc0, anc1, anc2, anc3, (float*)d_out);
}

// Round 16
// 155.095 us; speedup vs baseline: 1.2198x; 1.2198x over previous
//
#include <hip/hip_runtime.h>
#include <math.h>

#define TPB 256
static inline int cdiv(int a, int b) { return (a + b - 1) / b; }

typedef short bf8 __attribute__((ext_vector_type(8)));   // 8 bf16 (4 VGPRs)
typedef float f4 __attribute__((ext_vector_type(4)));    // mfma acc

__device__ inline float b2f(unsigned short u) {
    union { unsigned int i; float f; } v; v.i = ((unsigned int)u) << 16; return v.f;
}
__device__ inline short f2b(float f) {
    union { float f; unsigned int u; } v; v.f = f;
    unsigned int r = v.u + 0x7FFF + ((v.u >> 16) & 1);
    return (short)(r >> 16);
}

// ---------------- workspace offsets (in shorts) ----------------
#define OW1   0               // [11][96][64]
#define OW2   67584           // [5][256][512]  (480 pad 512)
#define OW3   722944          // [3][384][768]
#define OW4   1607680         // [3][384][1152]
#define OW5   2934784         // [3][256][1152]
#define OWRC  3819520         // [3][512][768]  wr|wc
#define OWH1  4999168         // 2 x [256][256]
#define OZT   5130240         // 2 x [8][16][256]
#define OWH2  5195776         // [30][256] bf16: ch_w2(10) | rh_w2(20)
#define OBIAS 5203456         // 1024 f32 (2048 shorts): br|bc|chb1|rhb1
#define OACT1 5205504
#define OP1   7062368
#define OACTB 7521472
#define OXF   9520064
#define OCRC  9695168

#define ACT2_OFF  0
#define POOL2_OFF 1083648
#define ACT3_OFF  1347840
#define ACT4_OFF  1695488

// ---------------- fused prep ----------------
__global__ __launch_bounds__(256) void wprep_k(
        const float* __restrict__ bb_w1, const float* __restrict__ bb_w2,
        const float* __restrict__ bb_w3, const float* __restrict__ bb_w4,
        const float* __restrict__ bb_w5,
        const float* __restrict__ wr, const float* __restrict__ wc,
        const float* __restrict__ ch_w1, const float* __restrict__ rh_w1,
        const float* __restrict__ ch_w2, const float* __restrict__ rh_w2,
        const float* __restrict__ z_cls, const float* __restrict__ z_reg,
        const float* __restrict__ br, const float* __restrict__ bc,
        const float* __restrict__ chb1, const float* __restrict__ rhb1,
        const float* __restrict__ x,
        short* __restrict__ W, float* __restrict__ biasf,
        short* __restrict__ xb) {
    __shared__ float lds[3465];   // up to K2*(C+1) = 9*385
    int bid = blockIdx.x;
    int t = threadIdx.x;

    if (bid < 1792) {
        const float* src;
        short* dst;
        int C, K2, Ot, KwC, orow;
        if (bid < 384)       { int o = bid;        C = 256; K2 = 9;  src = bb_w3 + (size_t)o * 2304; dst = W + OW3;  Ot = 384; KwC = 768;  orow = o; }
        else if (bid < 768)  { int o = bid - 384;  C = 384; K2 = 9;  src = bb_w4 + (size_t)o * 3456; dst = W + OW4;  Ot = 384; KwC = 1152; orow = o; }
        else if (bid < 1024) { int o = bid - 768;  C = 384; K2 = 9;  src = bb_w5 + (size_t)o * 3456; dst = W + OW5;  Ot = 256; KwC = 1152; orow = o; }
        else if (bid < 1280) { int o = bid - 1024; C = 256; K2 = 9;  src = wr    + (size_t)o * 2304; dst = W + OWRC; Ot = 512; KwC = 768;  orow = o; }
        else if (bid < 1536) { int o = bid - 1280; C = 256; K2 = 9;  src = wc    + (size_t)o * 2304; dst = W + OWRC; Ot = 512; KwC = 768;  orow = o + 256; }
        else                 { int o = bid - 1536; C = 96;  K2 = 25; src = bb_w2 + (size_t)o * 2400; dst = W + OW2;  Ot = 256; KwC = 512;  orow = o; }

        int n = C * K2;
        int Cp = C + 1;
        if (K2 == 9) {
            for (int i = t; i < n; i += 256) {
                int kk = i % 9, c = i / 9;
                lds[kk * Cp + c] = src[i];
            }
            __syncthreads();
#pragma unroll
            for (int kk = 0; kk < 9; ++kk) {
                int ki = kk / 3, kj = kk % 3;
                short* rowb = dst + ((size_t)ki * Ot + orow) * KwC + kj * C;
                for (int c = t; c < C; c += 256)
                    rowb[c] = f2b(lds[kk * Cp + c]);
            }
        } else {
            for (int i = t; i < n; i += 256) {
                int kk = i % 25, c = i / 25;
                lds[kk * Cp + c] = src[i];
            }
            __syncthreads();
            for (int kk = 0; kk < 25; ++kk) {
                int ki = kk / 5, kj = kk % 5;
                short* rowb = dst + ((size_t)ki * Ot + orow) * KwC + kj * C;
                if (t < C) rowb[t] = f2b(lds[kk * Cp + t]);
            }
            if (t < 160) {
                int ki = t / 32, kp = 480 + (t & 31);
                dst[((size_t)ki * Ot + orow) * KwC + kp] = 0;
            }
        }
        return;
    }

    int fidx = (bid - 1792) * 256 + t;
    if (fidx < 67584) {                               // Wt1 [11][96][64]
        int k = fidx & 63, o = (fidx >> 6) % 96, ki = fidx / (64 * 96);
        float v = 0.f;
        if (k < 33) v = bb_w1[o * 363 + (k % 3) * 121 + ki * 11 + (k / 3)];
        W[fidx] = f2b(v);
    } else if (fidx < 198656) {                       // Wh1 [256][256] x2
        int i = fidx - 67584;
        const float* src = (i < 65536) ? ch_w1 : rh_w1;
        W[OWH1 + i] = f2b(src[i & 65535]);
    } else if (fidx < 206336) {                       // Wh2 [30][256]
        int i = fidx - 198656;
        int o = i >> 8, c = i & 255;
        float v = (o < 10) ? ch_w2[o * 256 + c] : rh_w2[(o - 10) * 256 + c];
        W[OWH2 + i] = f2b(v);
    } else if (fidx < 271872) {                       // zt [8][16][256] x2
        int i = fidx - 206336;
        const float* src = (i < 32768) ? z_cls : z_reg;
        int j = i & 32767;
        int c = j & 255, k = (j >> 8) & 15, m = j >> 12;
        W[OZT + i] = f2b(src[m * 4096 + c * 16 + k]);
    } else if (fidx < 272896) {                       // biases 1024 f32
        int i = fidx - 271872;
        const float* src = (i < 256) ? br : (i < 512) ? bc : (i < 768) ? chb1 : rhb1;
        biasf[i] = src[i & 255];
    } else {                                          // xb f32->bf16
        int i = fidx - 272896;
        if (i < 247107) xb[i] = f2b(x[i]);
    }
}

// -------- implicit-GEMM, r8 dbuf structure + optional in-block split-K --------
// KSPLIT=2: 512 threads = 2 wave-groups; group g runs the r8 pipeline over its
// K-half in its OWN LDS half (serial chain halves), then partial f32 accs are
// reduced through LDS. Barriers are unconditional (same count for both groups,
// idle-padded for odd S). No extra dispatches, no atomics.
template <int BKC, int KSPLIT>
__global__ __launch_bounds__(KSPLIT * 256) void gemm_k(
        const short* __restrict__ in, const short* __restrict__ wt,
        const float* __restrict__ bias, short* __restrict__ out,
        int M, int N, int Wo, int CinW, int Cin,
        int S, int SPR, int aWrap, int bWrap, int KwCp,
        int relu, int msplit, int wsec, int bsec, int nt) {
    constexpr int BK = BKC * 32;
    constexpr int LDW = BK + 8;
    constexpr int CPR = BK / 8;
    constexpr int RPR = 256 / CPR;
    __shared__ short sa[KSPLIT][2][64 * LDW];
    __shared__ short sb[KSPLIT][2][64 * LDW];

    int bid = blockIdx.x;
    int m0 = (bid / nt) * 64, n0 = (bid % nt) * 64;
    int t = threadIdx.x;
    int wg = (KSPLIT == 2) ? (t >> 8) : 0;
    int t8 = t & 255;
    int lane = t8 & 63;
    int wid = t8 >> 6, wm = wid >> 1, wn = wid & 1;
    int sec = (m0 >= msplit) ? 1 : 0;
    const short* wts = wt + (size_t)sec * wsec;
    const float* bs = bias + sec * bsec;

    // K-split bounds: group g covers steps [g*Sh, g*Sh + nReal)
    int Sh, n1, nReal;
    if (KSPLIT == 2) {
        Sh = (S + 1) >> 1;
        n1 = wg * Sh;
        nReal = wg ? (S - Sh) : Sh;
    } else { Sh = S; n1 = 0; nReal = S; }
    int wraps = n1 / SPR;
    int srow = n1 % SPR;
    int offA0 = wraps * aWrap + (n1 - wraps) * BK;
    int offB0 = wraps * bWrap + (n1 - wraps) * BK;

    int rql = t8 / CPR;
    int ch8 = (t8 % CPR) * 8;

    const short* pA[BKC];
    const short* pB[BKC];
#pragma unroll
    for (int q = 0; q < BKC; ++q) {
        int mr = m0 + q * RPR + rql; if (mr > M - 1) mr = M - 1;
        int oy = mr / Wo, ox = mr - oy * Wo;
        pA[q] = in + (size_t)oy * CinW + (size_t)ox * Cin + ch8 + offA0;
        int nr = n0 + q * RPR + rql; if (nr > N - 1) nr = N - 1;
        pB[q] = wts + (size_t)nr * KwCp + ch8 + offB0;
    }
    int swb = rql * LDW + ch8;

    int arow = (wm * 32 + (lane & 15)) * LDW + (lane >> 4) * 8;
    int brow = (wn * 32 + (lane & 15)) * LDW + (lane >> 4) * 8;

    f4 acc[2][2] = {};
    bf8 va[BKC], vb[BKC];

#define LOAD_STEP()                                                           \
    do {                                                                      \
        _Pragma("unroll")                                                     \
        for (int q = 0; q < BKC; ++q) {                                       \
            va[q] = *(const bf8*)pA[q];                                       \
            vb[q] = *(const bf8*)pB[q];                                       \
        }                                                                     \
        if (++srow == SPR) {                                                  \
            srow = 0;                                                         \
            _Pragma("unroll")                                                 \
            for (int q = 0; q < BKC; ++q) { pA[q] += aWrap; pB[q] += bWrap; } \
        } else {                                                              \
            _Pragma("unroll")                                                 \
            for (int q = 0; q < BKC; ++q) { pA[q] += BK; pB[q] += BK; }       \
        }                                                                     \
    } while (0)

#define WRITE_LDS(buf)                                                        \
    do {                                                                      \
        _Pragma("unroll")                                                     \
        for (int q = 0; q < BKC; ++q) {                                       \
            *(bf8*)&sa[wg][buf][swb + q * (RPR * LDW)] = va[q];               \
            *(bf8*)&sb[wg][buf][swb + q * (RPR * LDW)] = vb[q];               \
        }                                                                     \
    } while (0)

#define MFMA_STEP(buf)                                                        \
    do {                                                                      \
        const short* A = sa[wg][buf];                                         \
        const short* B = sb[wg][buf];                                         \
        _Pragma("unroll")                                                     \
        for (int kc = 0; kc < BKC; ++kc) {                                    \
            bf8 a0 = *(const bf8*)&A[arow + kc * 32];                         \
            bf8 a1 = *(const bf8*)&A[arow + 16 * LDW + kc * 32];              \
            bf8 b0 = *(const bf8*)&B[brow + kc * 32];                         \
            bf8 b1 = *(const bf8*)&B[brow + 16 * LDW + kc * 32];              \
            acc[0][0] = __builtin_amdgcn_mfma_f32_16x16x32_bf16(a0, b0, acc[0][0], 0, 0, 0); \
            acc[0][1] = __builtin_amdgcn_mfma_f32_16x16x32_bf16(a0, b1, acc[0][1], 0, 0, 0); \
            acc[1][0] = __builtin_amdgcn_mfma_f32_16x16x32_bf16(a1, b0, acc[1][0], 0, 0, 0); \
            acc[1][1] = __builtin_amdgcn_mfma_f32_16x16x32_bf16(a1, b1, acc[1][1], 0, 0, 0); \
        }                                                                     \
    } while (0)

    if (nReal > 0) {
        LOAD_STEP();
        WRITE_LDS(0);
    }
    __syncthreads();

    for (int sloc = 0; sloc < Sh; ++sloc) {
        int cur = sloc & 1;
        bool act = sloc < nReal;
        bool pre = (sloc + 1 < nReal);
        if (pre) LOAD_STEP();
        if (act) MFMA_STEP(cur);
        if (pre) WRITE_LDS(cur ^ 1);
        __syncthreads();
    }
#undef LOAD_STEP
#undef WRITE_LDS
#undef MFMA_STEP

    if (KSPLIT == 2) {
        // group 1 -> LDS, group 0 adds (16 f32/thread; 16 KB, reuses sa)
        float* red = (float*)&sa[0][0][0];
        if (wg == 1) {
#pragma unroll
            for (int i = 0; i < 2; ++i)
#pragma unroll
                for (int j = 0; j < 2; ++j)
#pragma unroll
                    for (int r = 0; r < 4; ++r)
                        red[t8 * 16 + (i * 2 + j) * 4 + r] = acc[i][j][r];
        }
        __syncthreads();
        if (wg == 1) return;
#pragma unroll
        for (int i = 0; i < 2; ++i)
#pragma unroll
            for (int j = 0; j < 2; ++j)
#pragma unroll
                for (int r = 0; r < 4; ++r)
                    acc[i][j][r] += red[t8 * 16 + (i * 2 + j) * 4 + r];
    }

#pragma unroll
    for (int i = 0; i < 2; ++i) {
#pragma unroll
        for (int j = 0; j < 2; ++j) {
            int gm_base = m0 + wm * 32 + i * 16 + (lane >> 4) * 4;
            int gn = n0 + wn * 32 + j * 16 + (lane & 15);
            if (gn < N) {
                float bv = bs[gn];
#pragma unroll
                for (int r = 0; r < 4; ++r) {
                    int gm = gm_base + r;
                    if (gm < M) {
                        float v = acc[i][j][r] + bv;
                        if (relu) v = fmaxf(v, 0.f);
                        out[(size_t)gm * N + gn] = f2b(v);
                    }
                }
            }
        }
    }
}

// ---------------- maxpool 3x3 s2 + relu, NHWC bf16 ----------------
__global__ void pool_k(const short* __restrict__ in, short* __restrict__ out,
                       int C8, int Win, int Ho) {
    int idx = blockIdx.x * blockDim.x + threadIdx.x;
    int total = Ho * Ho * C8;
    if (idx >= total) return;
    int c8 = idx % C8;
    int p = idx / C8;
    int oy = p / Ho, ox = p % Ho;
    int C = C8 * 8;
    float mx[8];
#pragma unroll
    for (int e = 0; e < 8; ++e) mx[e] = -INFINITY;
#pragma unroll
    for (int ki = 0; ki < 3; ++ki)
#pragma unroll
        for (int kj = 0; kj < 3; ++kj) {
            const bf8 v = *(const bf8*)(in + ((size_t)(oy * 2 + ki) * Win + ox * 2 + kj) * C + c8 * 8);
#pragma unroll
            for (int e = 0; e < 8; ++e) mx[e] = fmaxf(mx[e], b2f((unsigned short)v[e]));
        }
    bf8 o;
#pragma unroll
    for (int e = 0; e < 8; ++e) o[e] = f2b(fmaxf(mx[e], 0.f));
    *(bf8*)(out + (size_t)p * C + c8 * 8) = o;
}

// ---------------- depthwise 4x4 correlation, both halves in one dispatch ----------------
__global__ void dwcorr_k(const short* __restrict__ crcb, const short* __restrict__ zt,
                         short* __restrict__ corr) {
    int idx = blockIdx.x * blockDim.x + threadIdx.x;
    if (idx >= 2 * 903168) return;
    int half = idx / 903168;
    int r = idx - half * 903168;
    int c = r & 255;
    int l = (r >> 8) % 441;
    int mb = r / (441 * 256);
    int y = l / 21, xx = l % 21;
    const short* ip = crcb + half * 256 + (size_t)(y * 24 + xx) * 512 + c;
    const short* zp = zt + half * 32768 + mb * 4096 + c;
    float acc = 0.f;
#pragma unroll
    for (int ki = 0; ki < 4; ++ki)
#pragma unroll
        for (int kj = 0; kj < 4; ++kj)
            acc = fmaf(b2f((unsigned short)ip[(ki * 24 + kj) * 512]),
                       b2f((unsigned short)zp[(ki * 4 + kj) * 256]), acc);
    corr[((size_t)(half * 3584 + mb * 441 + l)) * 256 + c] = f2b(acc);
}

// ---------------- fused head layer-2 + decode, 3 parallel output groups ----------------
__global__ void head2epi_k(const short* __restrict__ hid, const short* __restrict__ wh2,
                           const float* __restrict__ chb2, const float* __restrict__ rhb2,
                           const float* __restrict__ a0, const float* __restrict__ a1,
                           const float* __restrict__ a2, const float* __restrict__ a3,
                           float* __restrict__ out) {
    const int Ntot = 8 * 2205;
    int idx = blockIdx.x * blockDim.x + threadIdx.x;
    if (idx >= 3 * Ntot) return;
    int g = idx / Ntot;
    int r = idx - g * Ntot;
    int m = r / 2205, j = r % 2205;
    int a = j / 441, pos = j % 441;
    int ml = m * 441 + pos;
    const short* h = hid + (size_t)((g == 0) ? ml : 3584 + ml) * 256;
    int row0, row1;
    float acc0, acc1;
    if (g == 0)      { row0 = a;      row1 = 5 + a;  acc0 = chb2[a];      acc1 = chb2[5 + a];  }
    else if (g == 1) { row0 = 10 + a; row1 = 15 + a; acc0 = rhb2[a];      acc1 = rhb2[5 + a];  }
    else             { row0 = 20 + a; row1 = 25 + a; acc0 = rhb2[10 + a]; acc1 = rhb2[15 + a]; }
    const short* w0 = wh2 + row0 * 256;
    const short* w1 = wh2 + row1 * 256;
    for (int c = 0; c < 256; c += 8) {
        bf8 hv = *(const bf8*)(h + c);
        bf8 w0v = *(const bf8*)(w0 + c);
        bf8 w1v = *(const bf8*)(w1 + c);
#pragma unroll
        for (int e = 0; e < 8; ++e) {
            float hf = b2f((unsigned short)hv[e]);
            acc0 = fmaf(hf, b2f((unsigned short)w0v[e]), acc0);
            acc1 = fmaf(hf, b2f((unsigned short)w1v[e]), acc1);
        }
    }
    if (g == 0) {
        out[4 * Ntot + r] = 1.f / (1.f + expf(acc0 - acc1));
    } else if (g == 1) {
        out[0 * Ntot + r] = fmaf(acc0, a2[r], a0[r]);
        out[1 * Ntot + r] = fmaf(acc1, a3[r], a1[r]);
    } else {
        out[2 * Ntot + r] = expf(acc0) * a2[r];
        out[3 * Ntot + r] = expf(acc1) * a3[r];
    }
}

extern "C" void kernel_launch(void* const* d_in, const int* in_sizes, int n_in,
                              void* d_out, int out_size, void* d_ws, size_t ws_size,
                              hipStream_t stream) {
    const float* x     = (const float*)d_in[0];
    const float* z_reg = (const float*)d_in[1];
    const float* z_cls = (const float*)d_in[2];
    const float* bb_w1 = (const float*)d_in[3];
    const float* bb_b1 = (const float*)d_in[4];
    const float* bb_w2 = (const float*)d_in[5];
    const float* bb_b2 = (const float*)d_in[6];
    const float* bb_w3 = (const float*)d_in[7];
    const float* bb_b3 = (const float*)d_in[8];
    const float* bb_w4 = (const float*)d_in[9];
    const float* bb_b4 = (const float*)d_in[10];
    const float* bb_w5 = (const float*)d_in[11];
    const float* bb_b5 = (const float*)d_in[12];
    const float* wr    = (const float*)d_in[13];
    const float* br    = (const float*)d_in[14];
    const float* wc    = (const float*)d_in[15];
    const float* bc    = (const float*)d_in[16];
    const float* rh_w1 = (const float*)d_in[17];
    const float* rh_b1 = (const float*)d_in[18];
    const float* rh_w2 = (const float*)d_in[19];
    const float* rh_b2 = (const float*)d_in[20];
    const float* ch_w1 = (const float*)d_in[21];
    const float* ch_b1 = (const float*)d_in[22];
    const float* ch_w2 = (const float*)d_in[23];
    const float* ch_b2 = (const float*)d_in[24];
    const float* anc0  = (const float*)d_in[25];
    const float* anc1  = (const float*)d_in[26];
    const float* anc2  = (const float*)d_in[27];
    const float* anc3  = (const float*)d_in[28];

    short* sws  = (short*)d_ws;
    short* W    = sws;
    float* biasf = (float*)(sws + OBIAS);
    short* act1 = sws + OACT1;              // later: hid
    short* pool1 = sws + OP1;
    short* actB = sws + OACTB;
    short* xb   = actB;
    short* act2 = actB + ACT2_OFF;
    short* pool2 = actB + POOL2_OFF;
    short* act3 = actB + ACT3_OFF;
    short* act4 = actB + ACT4_OFF;
    short* corr = actB;
    short* xf   = sws + OXF;
    short* crcb = sws + OCRC;
    short* hid  = act1;

    const int BIG = 1 << 30;

    // 1. fused prep
    wprep_k<<<1792 + 2032, 256, 0, stream>>>(
        bb_w1, bb_w2, bb_w3, bb_w4, bb_w5, wr, wc, ch_w1, rh_w1, ch_w2, rh_w2,
        z_cls, z_reg, br, bc, ch_b1, rh_b1, x, W, biasf, xb);

    // 2. conv1: M=19321 N=96, 11 ki-rows of K=64 (33 real)
    gemm_k<2, 1><<<302 * 2, 256, 0, stream>>>(
        xb, W + OW1, bb_b1, act1,
        19321, 96, 139, 1722, 6,
        11, 1, 861, 6144, 64, 0, BIG, 0, 0, 2);
    pool_k<<<cdiv(69 * 69 * 12, TPB), TPB, 0, stream>>>(act1, pool1, 12, 139, 69);

    // 3. conv2: M=4225 N=256, K=5x512(480 real), S=20 (grid 268 -> no split)
    gemm_k<4, 1><<<67 * 4, 256, 0, stream>>>(
        pool1, W + OW2, bb_b2, act2,
        4225, 256, 65, 6624, 96,
        20, 4, 6240, 130688, 512, 0, BIG, 0, 0, 4);
    pool_k<<<cdiv(32 * 32 * 32, TPB), TPB, 0, stream>>>(act2, pool2, 32, 65, 32);

    // 4. conv3: S=18, grid 90 -> in-block split-K (2 x 9 steps)
    gemm_k<4, 2><<<15 * 6, 512, 0, stream>>>(
        pool2, W + OW3, bb_b3, act3,
        900, 384, 30, 8192, 256,
        18, 6, 7552, 294272, 768, 1, BIG, 0, 0, 6);

    // 5. conv4: S=27, grid 78 -> split-K (14+13)
    gemm_k<4, 2><<<13 * 6, 512, 0, stream>>>(
        act3, W + OW4, bb_b4, act4,
        784, 384, 28, 11520, 384,
        27, 9, 10496, 441344, 1152, 1, BIG, 0, 0, 6);

    // 6. conv5: S=27, grid 44 -> split-K (no relu)
    gemm_k<4, 2><<<11 * 4, 512, 0, stream>>>(
        act4, W + OW5, bb_b5, xf,
        676, 256, 26, 10752, 384,
        27, 9, 9728, 293888, 1152, 0, BIG, 0, 0, 4);

    // 7. conv_reg2|conv_cls2 fused: N=512, S=18, grid 72 -> split-K
    gemm_k<4, 2><<<9 * 8, 512, 0, stream>>>(
        xf, W + OWRC, biasf, crcb,
        576, 512, 24, 6656, 256,
        18, 6, 6016, 392576, 768, 1, BIG, 0, 0, 8);

    // 8. depthwise correlation (both halves)
    dwcorr_k<<<cdiv(2 * 903168, TPB), TPB, 0, stream>>>(crcb, W + OZT, corr);

    // 9. head layer-1: M=7112 (split 3584), K=256, S=2 (grid 448 -> no split)
    gemm_k<4, 1><<<112 * 4, 256, 0, stream>>>(
        corr, W + OWH1, biasf + 512, hid,
        7112, 256, 7112, 0, 256,
        2, 2, 0, 0, 256, 1, 3584, 65536, 256, 4);

    // 10. fused head layer-2 + decode
    head2epi_k<<<cdiv(3 * 8 * 2205, TPB), TPB, 0, stream>>>(
        hid, W + OWH2, ch_b2, rh_b2, anc0, anc1, anc2, anc3, (float*)d_out);
}